// Round 4
// baseline (1089.212 us; speedup 1.0000x reference)
//
#include <hip/hip_runtime.h>
#include <math.h>

namespace {
constexpr int B_    = 8;
constexpr int NIN   = 32;
constexpr int H_    = 14;
constexpr int CIN   = 8;
constexpr int C_    = 32;
constexpr int COUT  = 16;
constexpr int R_    = 288;
constexpr int W_    = 12;
constexpr int NITER = 3;
constexpr size_t XSUB = (size_t)NIN * H_ * H_ * CIN;   // x stride per batch elem
}

__device__ __forceinline__ float dot4(const float4 a, const float4 b) {
    return fmaf(a.x, b.x, fmaf(a.y, b.y, fmaf(a.z, b.z, a.w * b.w)));
}

// Priors for (r, outputs og*4..og*4+3), batch elems b0 and b0+1; W float4s
// read once and shared by both subs. Two 4-i chunks keep live W regs at 16.
__device__ __forceinline__ void prior_one(const float* __restrict__ x0,
                                          const float* __restrict__ rwc,
                                          int r, int p, int q, int og,
                                          float4& a0, float4& a1)
{
    const int n   = r / 9;
    const int rem = r - n * 9;
    const int kh  = rem / 3;
    const int kw  = rem - kh * 3;
    const float* xp = x0 + ((n * H_ + (p + kh)) * H_ + (q + kw)) * CIN;
    const float4* wp = (const float4*)(rwc + (size_t)r * CIN * COUT) + og;
    float4 r0 = make_float4(0.f, 0.f, 0.f, 0.f);
    float4 r1 = make_float4(0.f, 0.f, 0.f, 0.f);
    {   // i = 0..3
        const float4 xa = *(const float4*)xp;
        const float4 ya = *(const float4*)(xp + XSUB);
        const float xs0[4] = {xa.x, xa.y, xa.z, xa.w};
        const float xs1[4] = {ya.x, ya.y, ya.z, ya.w};
        #pragma unroll
        for (int i = 0; i < 4; ++i) {
            const float4 wv = wp[i * 4];
            r0.x = fmaf(xs0[i], wv.x, r0.x);  r1.x = fmaf(xs1[i], wv.x, r1.x);
            r0.y = fmaf(xs0[i], wv.y, r0.y);  r1.y = fmaf(xs1[i], wv.y, r1.y);
            r0.z = fmaf(xs0[i], wv.z, r0.z);  r1.z = fmaf(xs1[i], wv.z, r1.z);
            r0.w = fmaf(xs0[i], wv.w, r0.w);  r1.w = fmaf(xs1[i], wv.w, r1.w);
        }
    }
    {   // i = 4..7
        const float4 xb = *(const float4*)(xp + 4);
        const float4 yb = *(const float4*)(xp + XSUB + 4);
        const float xs0[4] = {xb.x, xb.y, xb.z, xb.w};
        const float xs1[4] = {yb.x, yb.y, yb.z, yb.w};
        #pragma unroll
        for (int i = 0; i < 4; ++i) {
            const float4 wv = wp[(4 + i) * 4];
            r0.x = fmaf(xs0[i], wv.x, r0.x);  r1.x = fmaf(xs1[i], wv.x, r1.x);
            r0.y = fmaf(xs0[i], wv.y, r0.y);  r1.y = fmaf(xs1[i], wv.y, r1.y);
            r0.z = fmaf(xs0[i], wv.z, r0.z);  r1.z = fmaf(xs1[i], wv.z, r1.z);
            r0.w = fmaf(xs0[i], wv.w, r0.w);  r1.w = fmaf(xs1[i], wv.w, r1.w);
        }
    }
    a0 = r0; a1 = r1;
}

// One block per (c, b-pair, p, q). Priors AND logits live in registers.
// Thread (og = tid&3, rl = tid>>2) owns r = rl + 64j (j=0..3; + r = 256+rl
// for rl<32, wave-uniform) x outputs og*4..og*4+3 x both batch elems.
// After the og-butterfly every lane of an og-quad holds the full
// sum_o(pri*v), so logits (and exp) are maintained redundantly per lane —
// no LDS logits/probs, no separate softmax passes. 2 barriers per iter.
__global__ __launch_bounds__(256, 5)
void caps_route4(const float* __restrict__ x,
                 const float* __restrict__ rw,
                 float* __restrict__ out)
{
    const int tid = threadIdx.x;
    const int p  = blockIdx.x / W_;
    const int q  = blockIdx.x % W_;
    const int b0 = blockIdx.y * 2;
    const int c  = blockIdx.z;

    __shared__ float sRed[4][2][16];   // per-wave partial s
    __shared__ float redE[2][4];       // per-wave sum of exp
    __shared__ float vS[2][16];        // squashed v broadcast

    const int og   = tid & 3;
    const int rl   = tid >> 2;
    const int lane = tid & 63;
    const int wv   = tid >> 6;
    const bool hasJ4 = (rl < 32);      // waves 0,1 — wave-uniform predicate

    // ---- priors in registers
    const float* x0  = x + (size_t)b0 * XSUB;
    const float* rwc = rw + (size_t)c * R_ * CIN * COUT;
    float4 acc[5][2];
    #pragma unroll
    for (int j = 0; j < 4; ++j)
        prior_one(x0, rwc, rl + 64 * j, p, q, og, acc[j][0], acc[j][1]);
    if (hasJ4)
        prior_one(x0, rwc, 256 + rl, p, q, og, acc[4][0], acc[4][1]);

    // logits, register-resident (identical across each og-quad)
    float lg0[5] = {0.f, 0.f, 0.f, 0.f, 0.f};
    float lg1[5] = {0.f, 0.f, 0.f, 0.f, 0.f};

    for (int it = 0; it < NITER; ++it) {
        float4 s0 = make_float4(0.f, 0.f, 0.f, 0.f);
        float4 s1 = make_float4(0.f, 0.f, 0.f, 0.f);
        float se0 = 0.f, se1 = 0.f;

        if (it == 0) {
            // probs uniform: s = sum_r pri (1/R folded into squash)
            #pragma unroll
            for (int j = 0; j < 4; ++j) {
                s0.x += acc[j][0].x;  s1.x += acc[j][1].x;
                s0.y += acc[j][0].y;  s1.y += acc[j][1].y;
                s0.z += acc[j][0].z;  s1.z += acc[j][1].z;
                s0.w += acc[j][0].w;  s1.w += acc[j][1].w;
            }
            if (hasJ4) {
                s0.x += acc[4][0].x;  s1.x += acc[4][1].x;
                s0.y += acc[4][0].y;  s1.y += acc[4][1].y;
                s0.z += acc[4][0].z;  s1.z += acc[4][1].z;
                s0.w += acc[4][0].w;  s1.w += acc[4][1].w;
            }
        } else {
            const float4 v0 = *(const float4*)&vS[0][og * 4];
            const float4 v1 = *(const float4*)&vS[1][og * 4];
            #pragma unroll
            for (int j = 0; j < 4; ++j) {
                float d0 = dot4(acc[j][0], v0);
                float d1 = dot4(acc[j][1], v1);
                d0 += __shfl_xor(d0, 1, 64);  d1 += __shfl_xor(d1, 1, 64);
                d0 += __shfl_xor(d0, 2, 64);  d1 += __shfl_xor(d1, 2, 64);
                lg0[j] += d0;                 lg1[j] += d1;
                const float e0 = expf(lg0[j]);
                const float e1 = expf(lg1[j]);
                se0 += e0;                    se1 += e1;
                s0.x = fmaf(e0, acc[j][0].x, s0.x);  s1.x = fmaf(e1, acc[j][1].x, s1.x);
                s0.y = fmaf(e0, acc[j][0].y, s0.y);  s1.y = fmaf(e1, acc[j][1].y, s1.y);
                s0.z = fmaf(e0, acc[j][0].z, s0.z);  s1.z = fmaf(e1, acc[j][1].z, s1.z);
                s0.w = fmaf(e0, acc[j][0].w, s0.w);  s1.w = fmaf(e1, acc[j][1].w, s1.w);
            }
            if (hasJ4) {
                float d0 = dot4(acc[4][0], v0);
                float d1 = dot4(acc[4][1], v1);
                d0 += __shfl_xor(d0, 1, 64);  d1 += __shfl_xor(d1, 1, 64);
                d0 += __shfl_xor(d0, 2, 64);  d1 += __shfl_xor(d1, 2, 64);
                lg0[4] += d0;                 lg1[4] += d1;
                const float e0 = expf(lg0[4]);
                const float e1 = expf(lg1[4]);
                se0 += e0;                    se1 += e1;
                s0.x = fmaf(e0, acc[4][0].x, s0.x);  s1.x = fmaf(e1, acc[4][1].x, s1.x);
                s0.y = fmaf(e0, acc[4][0].y, s0.y);  s1.y = fmaf(e1, acc[4][1].y, s1.y);
                s0.z = fmaf(e0, acc[4][0].z, s0.z);  s1.z = fmaf(e1, acc[4][1].z, s1.z);
                s0.w = fmaf(e0, acc[4][0].w, s0.w);  s1.w = fmaf(e1, acc[4][1].w, s1.w);
            }
            // se identical across og lanes -> reduce over rl bits only
            #pragma unroll
            for (int off = 4; off <= 32; off <<= 1) {
                se0 += __shfl_xor(se0, off, 64);
                se1 += __shfl_xor(se1, off, 64);
            }
            if (lane == 0) { redE[0][wv] = se0; redE[1][wv] = se1; }
        }

        // reduce s over rl bits within wave (1/sum_e applied in squash)
        #pragma unroll
        for (int off = 4; off <= 32; off <<= 1) {
            s0.x += __shfl_xor(s0.x, off, 64);  s1.x += __shfl_xor(s1.x, off, 64);
            s0.y += __shfl_xor(s0.y, off, 64);  s1.y += __shfl_xor(s1.y, off, 64);
            s0.z += __shfl_xor(s0.z, off, 64);  s1.z += __shfl_xor(s1.z, off, 64);
            s0.w += __shfl_xor(s0.w, off, 64);  s1.w += __shfl_xor(s1.w, off, 64);
        }
        if (lane < 4) {   // lane == og here
            *(float4*)&sRed[wv][0][lane * 4] = s0;
            *(float4*)&sRed[wv][1][lane * 4] = s1;
        }
        __syncthreads();

        // ---- squash (32 threads: sb, o); inv folded in here
        if (tid < 32) {
            const int sb = tid >> 4;
            const int o  = tid & 15;
            const float inv = (it == 0)
                ? (1.0f / (float)R_)
                : 1.0f / (redE[sb][0] + redE[sb][1] + redE[sb][2] + redE[sb][3]);
            float s = (sRed[0][sb][o] + sRed[1][sb][o]
                     + sRed[2][sb][o] + sRed[3][sb][o]) * inv;
            float sn = s * s;
            #pragma unroll
            for (int off = 1; off <= 8; off <<= 1) sn += __shfl_xor(sn, off, 64);
            const float v = s * (sqrtf(sn) / (1.0f + sn));
            if (it == NITER - 1) {
                out[((((size_t)(b0 + sb) * C_ + c) * W_ + p) * W_ + q) * COUT + o] = v;
            } else {
                vS[sb][o] = v;
            }
        }
        if (it == NITER - 1) break;
        __syncthreads();   // vS visible to all before next iteration
    }
}

extern "C" void kernel_launch(void* const* d_in, const int* in_sizes, int n_in,
                              void* d_out, int out_size, void* d_ws, size_t ws_size,
                              hipStream_t stream) {
    const float* x  = (const float*)d_in[0];
    const float* rw = (const float*)d_in[1];
    float* out = (float*)d_out;
    dim3 grid(W_ * W_, B_ / 2, C_);
    caps_route4<<<grid, 256, 0, stream>>>(x, rw, out);
}

// Round 5
// 308.260 us; speedup vs baseline: 3.5334x; 3.5334x over previous
//
#include <hip/hip_runtime.h>
#include <math.h>

namespace {
constexpr int B_    = 8;
constexpr int NIN   = 32;
constexpr int H_    = 14;
constexpr int CIN   = 8;
constexpr int C_    = 32;
constexpr int COUT  = 16;
constexpr int R_    = 288;
constexpr int W_    = 12;
constexpr int NITER = 3;
constexpr size_t XSUB = (size_t)NIN * H_ * H_ * CIN;   // x stride per batch elem
}

__device__ __forceinline__ float dot4(const float4 a, const float4 b) {
    return fmaf(a.x, b.x, fmaf(a.y, b.y, fmaf(a.z, b.z, a.w * b.w)));
}

// Priors for (r, outputs og*4..og*4+3), batch elems b0 and b0+1; W float4s
// read once and shared by both subs. All loads issued up front (MLP).
__device__ __forceinline__ void prior_one(const float* __restrict__ x0,
                                          const float* __restrict__ rwc,
                                          int r, int p, int q, int og,
                                          float4& a0, float4& a1)
{
    const int n   = r / 9;
    const int rem = r - n * 9;
    const int kh  = rem / 3;
    const int kw  = rem - kh * 3;
    const float* xp = x0 + ((n * H_ + (p + kh)) * H_ + (q + kw)) * CIN;
    const float4 xa = *(const float4*)xp;
    const float4 xb = *(const float4*)(xp + 4);
    const float4 ya = *(const float4*)(xp + XSUB);
    const float4 yb = *(const float4*)(xp + XSUB + 4);
    const float xs0[8] = {xa.x, xa.y, xa.z, xa.w, xb.x, xb.y, xb.z, xb.w};
    const float xs1[8] = {ya.x, ya.y, ya.z, ya.w, yb.x, yb.y, yb.z, yb.w};
    const float4* wp = (const float4*)(rwc + (size_t)r * CIN * COUT) + og;
    float4 r0 = make_float4(0.f, 0.f, 0.f, 0.f);
    float4 r1 = make_float4(0.f, 0.f, 0.f, 0.f);
    #pragma unroll
    for (int i = 0; i < CIN; ++i) {
        const float4 wv = wp[i * 4];
        r0.x = fmaf(xs0[i], wv.x, r0.x);  r1.x = fmaf(xs1[i], wv.x, r1.x);
        r0.y = fmaf(xs0[i], wv.y, r0.y);  r1.y = fmaf(xs1[i], wv.y, r1.y);
        r0.z = fmaf(xs0[i], wv.z, r0.z);  r1.z = fmaf(xs1[i], wv.z, r1.z);
        r0.w = fmaf(xs0[i], wv.w, r0.w);  r1.w = fmaf(xs1[i], wv.w, r1.w);
    }
    a0 = r0; a1 = r1;
}

// One block per (c, b-pair, p, q). Priors AND logits live in registers.
// Thread (og = tid&3, rl = tid>>2) owns r = rl + 64j (j=0..3; + r = 256+rl
// for rl<32, wave-uniform) x outputs og*4..og*4+3 x both batch elems.
// After the og-butterfly every lane of an og-quad holds the full
// sum_o(pri*v), so logits (and exp) are maintained redundantly per lane —
// no LDS logits/probs, no separate softmax passes. ~2 barriers per iter.
// NOTE: plain launch_bounds — forcing 5 waves/EU (R4) spilled ~50 regs to
// scratch: VGPR 128->48, hbm_bytes 27MB->4.5GB, dur 340->1089us.
__global__ __launch_bounds__(256)
void caps_route5(const float* __restrict__ x,
                 const float* __restrict__ rw,
                 float* __restrict__ out)
{
    const int tid = threadIdx.x;
    const int p  = blockIdx.x / W_;
    const int q  = blockIdx.x % W_;
    const int b0 = blockIdx.y * 2;
    const int c  = blockIdx.z;

    __shared__ float sRed[4][2][16];   // per-wave partial s
    __shared__ float redE[2][4];       // per-wave sum of exp
    __shared__ float vS[2][16];        // squashed v broadcast

    const int og   = tid & 3;
    const int rl   = tid >> 2;
    const int lane = tid & 63;
    const int wv   = tid >> 6;
    const bool hasJ4 = (rl < 32);      // waves 0,1 — wave-uniform predicate

    // ---- priors in registers
    const float* x0  = x + (size_t)b0 * XSUB;
    const float* rwc = rw + (size_t)c * R_ * CIN * COUT;
    float4 acc[5][2];
    #pragma unroll
    for (int j = 0; j < 4; ++j)
        prior_one(x0, rwc, rl + 64 * j, p, q, og, acc[j][0], acc[j][1]);
    if (hasJ4)
        prior_one(x0, rwc, 256 + rl, p, q, og, acc[4][0], acc[4][1]);

    // logits, register-resident (identical across each og-quad)
    float lg0[5] = {0.f, 0.f, 0.f, 0.f, 0.f};
    float lg1[5] = {0.f, 0.f, 0.f, 0.f, 0.f};

    for (int it = 0; it < NITER; ++it) {
        float4 s0 = make_float4(0.f, 0.f, 0.f, 0.f);
        float4 s1 = make_float4(0.f, 0.f, 0.f, 0.f);
        float se0 = 0.f, se1 = 0.f;

        if (it == 0) {
            // probs uniform: s = sum_r pri (1/R folded into squash)
            #pragma unroll
            for (int j = 0; j < 4; ++j) {
                s0.x += acc[j][0].x;  s1.x += acc[j][1].x;
                s0.y += acc[j][0].y;  s1.y += acc[j][1].y;
                s0.z += acc[j][0].z;  s1.z += acc[j][1].z;
                s0.w += acc[j][0].w;  s1.w += acc[j][1].w;
            }
            if (hasJ4) {
                s0.x += acc[4][0].x;  s1.x += acc[4][1].x;
                s0.y += acc[4][0].y;  s1.y += acc[4][1].y;
                s0.z += acc[4][0].z;  s1.z += acc[4][1].z;
                s0.w += acc[4][0].w;  s1.w += acc[4][1].w;
            }
        } else {
            const float4 v0 = *(const float4*)&vS[0][og * 4];
            const float4 v1 = *(const float4*)&vS[1][og * 4];
            #pragma unroll
            for (int j = 0; j < 4; ++j) {
                float d0 = dot4(acc[j][0], v0);
                float d1 = dot4(acc[j][1], v1);
                d0 += __shfl_xor(d0, 1, 64);  d1 += __shfl_xor(d1, 1, 64);
                d0 += __shfl_xor(d0, 2, 64);  d1 += __shfl_xor(d1, 2, 64);
                lg0[j] += d0;                 lg1[j] += d1;
                const float e0 = expf(lg0[j]);
                const float e1 = expf(lg1[j]);
                se0 += e0;                    se1 += e1;
                s0.x = fmaf(e0, acc[j][0].x, s0.x);  s1.x = fmaf(e1, acc[j][1].x, s1.x);
                s0.y = fmaf(e0, acc[j][0].y, s0.y);  s1.y = fmaf(e1, acc[j][1].y, s1.y);
                s0.z = fmaf(e0, acc[j][0].z, s0.z);  s1.z = fmaf(e1, acc[j][1].z, s1.z);
                s0.w = fmaf(e0, acc[j][0].w, s0.w);  s1.w = fmaf(e1, acc[j][1].w, s1.w);
            }
            if (hasJ4) {
                float d0 = dot4(acc[4][0], v0);
                float d1 = dot4(acc[4][1], v1);
                d0 += __shfl_xor(d0, 1, 64);  d1 += __shfl_xor(d1, 1, 64);
                d0 += __shfl_xor(d0, 2, 64);  d1 += __shfl_xor(d1, 2, 64);
                lg0[4] += d0;                 lg1[4] += d1;
                const float e0 = expf(lg0[4]);
                const float e1 = expf(lg1[4]);
                se0 += e0;                    se1 += e1;
                s0.x = fmaf(e0, acc[4][0].x, s0.x);  s1.x = fmaf(e1, acc[4][1].x, s1.x);
                s0.y = fmaf(e0, acc[4][0].y, s0.y);  s1.y = fmaf(e1, acc[4][1].y, s1.y);
                s0.z = fmaf(e0, acc[4][0].z, s0.z);  s1.z = fmaf(e1, acc[4][1].z, s1.z);
                s0.w = fmaf(e0, acc[4][0].w, s0.w);  s1.w = fmaf(e1, acc[4][1].w, s1.w);
            }
            // se identical across og lanes -> reduce over rl bits only
            #pragma unroll
            for (int off = 4; off <= 32; off <<= 1) {
                se0 += __shfl_xor(se0, off, 64);
                se1 += __shfl_xor(se1, off, 64);
            }
            if (lane == 0) { redE[0][wv] = se0; redE[1][wv] = se1; }
        }

        // reduce s over rl bits within wave (1/sum_e applied in squash)
        #pragma unroll
        for (int off = 4; off <= 32; off <<= 1) {
            s0.x += __shfl_xor(s0.x, off, 64);  s1.x += __shfl_xor(s1.x, off, 64);
            s0.y += __shfl_xor(s0.y, off, 64);  s1.y += __shfl_xor(s1.y, off, 64);
            s0.z += __shfl_xor(s0.z, off, 64);  s1.z += __shfl_xor(s1.z, off, 64);
            s0.w += __shfl_xor(s0.w, off, 64);  s1.w += __shfl_xor(s1.w, off, 64);
        }
        if (lane < 4) {   // lane == og here
            *(float4*)&sRed[wv][0][lane * 4] = s0;
            *(float4*)&sRed[wv][1][lane * 4] = s1;
        }
        __syncthreads();

        // ---- squash (32 threads: sb, o); inv folded in here
        if (tid < 32) {
            const int sb = tid >> 4;
            const int o  = tid & 15;
            const float inv = (it == 0)
                ? (1.0f / (float)R_)
                : 1.0f / (redE[sb][0] + redE[sb][1] + redE[sb][2] + redE[sb][3]);
            float s = (sRed[0][sb][o] + sRed[1][sb][o]
                     + sRed[2][sb][o] + sRed[3][sb][o]) * inv;
            float sn = s * s;
            #pragma unroll
            for (int off = 1; off <= 8; off <<= 1) sn += __shfl_xor(sn, off, 64);
            const float v = s * (sqrtf(sn) / (1.0f + sn));
            if (it == NITER - 1) {
                out[((((size_t)(b0 + sb) * C_ + c) * W_ + p) * W_ + q) * COUT + o] = v;
            } else {
                vS[sb][o] = v;
            }
        }
        if (it == NITER - 1) break;
        __syncthreads();   // vS visible to all before next iteration
    }
}

extern "C" void kernel_launch(void* const* d_in, const int* in_sizes, int n_in,
                              void* d_out, int out_size, void* d_ws, size_t ws_size,
                              hipStream_t stream) {
    const float* x  = (const float*)d_in[0];
    const float* rw = (const float*)d_in[1];
    float* out = (float*)d_out;
    dim3 grid(W_ * W_, B_ / 2, C_);
    caps_route5<<<grid, 256, 0, stream>>>(x, rw, out);
}